// Round 1
// baseline (2391.085 us; speedup 1.0000x reference)
//
#include <hip/hip_runtime.h>

// Problem constants (G=1024 grid, known structure)
#define GSZ   1024
#define NV    (GSZ*GSZ)           // 1048576 vertices
#define N3    (NV*3)              // 3145728 floats per [NV,3] array
#define N4    (N3/4)              // 786432 float4s
#define FH    ((GSZ-1)*(GSZ-1))   // 1046529 faces in first half
#define NF    (2*FH)              // 2093058 total faces
#define O1    N3                  // centroid offset in d_out (floats)
#define O2    (O1 + 3*NF)         // fn offset
#define O3    (O2 + 3*NF)         // vn offset
#define LAMBDA 10.0f
#define CG_ITERS 64

// deterministic block sum (double), valid on thread 0
__device__ __forceinline__ double blk_sum(double v) {
#pragma unroll
  for (int off = 32; off > 0; off >>= 1) v += __shfl_down(v, off, 64);
  __shared__ double sm[16];
  int lane = threadIdx.x & 63;
  int wid  = threadIdx.x >> 6;
  if (lane == 0) sm[wid] = v;
  __syncthreads();
  double r = 0.0;
  if (threadIdx.x == 0) {
    int nw = (blockDim.x + 63) >> 6;
    for (int w = 0; w < nw; ++w) r += sm[w];
  }
  return r;
}

// x=0, r=p=u, partial += u.u
__global__ __launch_bounds__(256) void k_init(const float4* __restrict__ u,
    float4* __restrict__ x, float4* __restrict__ r, float4* __restrict__ p,
    double* __restrict__ part) {
  int t = blockIdx.x * 256 + threadIdx.x;
  float4 v = u[t];
  x[t] = make_float4(0.f, 0.f, 0.f, 0.f);
  r[t] = v;
  p[t] = v;
  double d = (double)v.x*v.x + (double)v.y*v.y + (double)v.z*v.z + (double)v.w*v.w;
  double s = blk_sum(d);
  if (threadIdx.x == 0) part[blockIdx.x] = s;
}

// q = (I + lam*L) p  (6-neighbor stencil), partial += p.q
__global__ __launch_bounds__(256) void k_mv(const float* __restrict__ p,
    float* __restrict__ q, double* __restrict__ part) {
  int t = blockIdx.x * 256 + threadIdx.x;
  int i = t >> 10, j = t & (GSZ - 1);
  float p0 = p[3*t], p1 = p[3*t+1], p2 = p[3*t+2];
  float n0 = 0.f, n1 = 0.f, n2 = 0.f;
  int deg = 0;
#define ACC(idx) { int u_ = (idx); n0 += p[3*u_]; n1 += p[3*u_+1]; n2 += p[3*u_+2]; deg++; }
  if (j > 0)                 ACC(t - 1);
  if (j < GSZ-1)             ACC(t + 1);
  if (i > 0)                 ACC(t - GSZ);
  if (i < GSZ-1)             ACC(t + GSZ);
  if (i < GSZ-1 && j > 0)    ACC(t + GSZ - 1);   // (i+1, j-1)
  if (i > 0 && j < GSZ-1)    ACC(t - GSZ + 1);   // (i-1, j+1)
#undef ACC
  float diag = 1.0f + LAMBDA * (float)deg;
  float q0 = diag*p0 - LAMBDA*n0;
  float q1 = diag*p1 - LAMBDA*n1;
  float q2 = diag*p2 - LAMBDA*n2;
  q[3*t] = q0; q[3*t+1] = q1; q[3*t+2] = q2;
  double d = (double)p0*q0 + (double)p1*q1 + (double)p2*q2;
  double s = blk_sum(d);
  if (threadIdx.x == 0) part[blockIdx.x] = s;
}

// x += alpha p ; r -= alpha q ; partial += r.r
__global__ __launch_bounds__(256) void k_xr(float4* __restrict__ x,
    float4* __restrict__ r, const float4* __restrict__ p,
    const float4* __restrict__ q, const double* __restrict__ s,
    double* __restrict__ part) {
  int t = blockIdx.x * 256 + threadIdx.x;
  float a = (float)s[1];
  float4 xv = x[t], pv = p[t], rv = r[t], qv = q[t];
  xv.x += a*pv.x; xv.y += a*pv.y; xv.z += a*pv.z; xv.w += a*pv.w;
  rv.x -= a*qv.x; rv.y -= a*qv.y; rv.z -= a*qv.z; rv.w -= a*qv.w;
  x[t] = xv; r[t] = rv;
  double d = (double)rv.x*rv.x + (double)rv.y*rv.y
           + (double)rv.z*rv.z + (double)rv.w*rv.w;
  double ss = blk_sum(d);
  if (threadIdx.x == 0) part[blockIdx.x] = ss;
}

// p = r + beta p
__global__ __launch_bounds__(256) void k_p(float4* __restrict__ p,
    const float4* __restrict__ r, const double* __restrict__ s) {
  int t = blockIdx.x * 256 + threadIdx.x;
  float b = (float)s[2];
  float4 pv = p[t], rv = r[t];
  pv.x = rv.x + b*pv.x; pv.y = rv.y + b*pv.y;
  pv.z = rv.z + b*pv.z; pv.w = rv.w + b*pv.w;
  p[t] = pv;
}

// reduce partials -> scalar ops
// mode 0: s[0] = tot           (gamma init)
// mode 1: s[1] = s[0]/tot      (alpha = gamma/pq)
// mode 2: s[2] = tot/s[0]; s[0] = tot   (beta, gamma update)
__global__ __launch_bounds__(1024) void k_reduce(const double* __restrict__ part,
    int n, double* __restrict__ s, int mode) {
  double v = 0.0;
  for (int idx = threadIdx.x; idx < n; idx += 1024) v += part[idx];
  double tot = blk_sum(v);
  if (threadIdx.x == 0) {
    if (mode == 0)      { s[0] = tot; }
    else if (mode == 1) { s[1] = s[0] / tot; }
    else                { s[2] = tot / s[0]; s[0] = tot; }
  }
}

// per-face centroid + normalized cross
__global__ __launch_bounds__(256) void k_faces(const float* __restrict__ v,
    float* __restrict__ cen, float* __restrict__ fn) {
  int f = blockIdx.x * 256 + threadIdx.x;
  if (f >= NF) return;
  int second = (f >= FH) ? 1 : 0;
  int cell = second ? f - FH : f;
  int ci = cell / (GSZ-1);
  int cj = cell - ci * (GSZ-1);
  int v00 = ci * GSZ + cj;
  int a0, a1, a2;
  if (!second) { a0 = v00;     a1 = v00 + 1;       a2 = v00 + GSZ; }
  else         { a0 = v00 + 1; a1 = v00 + GSZ + 1; a2 = v00 + GSZ; }
  float x0 = v[3*a0], y0 = v[3*a0+1], z0 = v[3*a0+2];
  float x1 = v[3*a1], y1 = v[3*a1+1], z1 = v[3*a1+2];
  float x2 = v[3*a2], y2 = v[3*a2+1], z2 = v[3*a2+2];
  const float third = 1.0f / 3.0f;
  cen[3*f]   = (x0 + x1 + x2) * third;
  cen[3*f+1] = (y0 + y1 + y2) * third;
  cen[3*f+2] = (z0 + z1 + z2) * third;
  float ax = x1-x0, ay = y1-y0, az = z1-z0;
  float bx = x2-x0, by = y2-y0, bz = z2-z0;
  float cx = ay*bz - az*by;
  float cy = az*bx - ax*bz;
  float cz = ax*by - ay*bx;
  float nrm = sqrtf(cx*cx + cy*cy + cz*cz);
  float inv = 1.0f / fmaxf(nrm, 1e-12f);
  fn[3*f] = cx*inv; fn[3*f+1] = cy*inv; fn[3*f+2] = cz*inv;
}

// per-vertex: gather <=6 adjacent face normals, sum, normalize
__global__ __launch_bounds__(256) void k_vn(const float* __restrict__ fn,
    float* __restrict__ vn) {
  int t = blockIdx.x * 256 + threadIdx.x;
  int i = t >> 10, j = t & (GSZ - 1);
  float s0 = 0.f, s1 = 0.f, s2 = 0.f;
  bool iN = (i >= 1), iS = (i <= GSZ-2), jW = (j >= 1), jE = (j <= GSZ-2);
  int rowi = i * (GSZ-1);
#define ADD(fidx) { int f_ = (fidx); s0 += fn[3*f_]; s1 += fn[3*f_+1]; s2 += fn[3*f_+2]; }
  // f1(a,b) = a*1023+b contains (a,b),(a,b+1),(a+1,b)
  if (iS && jE) ADD(rowi + j);
  if (iS && jW) ADD(rowi + j - 1);
  if (iN && jE) ADD(rowi - (GSZ-1) + j);
  // f2(a,b) = FH + a*1023+b contains (a,b+1),(a+1,b+1),(a+1,b)
  if (iS && jW) ADD(FH + rowi + j - 1);
  if (iN && jW) ADD(FH + rowi - (GSZ-1) + j - 1);
  if (iN && jE) ADD(FH + rowi - (GSZ-1) + j);
#undef ADD
  float nrm = sqrtf(s0*s0 + s1*s1 + s2*s2);
  float inv = 1.0f / fmaxf(nrm, 1e-12f);
  vn[3*t] = s0*inv; vn[3*t+1] = s1*inv; vn[3*t+2] = s2*inv;
}

extern "C" void kernel_launch(void* const* d_in, const int* in_sizes, int n_in,
                              void* d_out, int out_size, void* d_ws, size_t ws_size,
                              hipStream_t stream) {
  const float* u = (const float*)d_in[0];
  float* out = (float*)d_out;

  // output regions
  float* x   = out;        // verts accumulate here directly
  float* cen = out + O1;
  float* fn  = out + O2;
  float* vn  = out + O3;

  // CG scratch lives in the tail of d_out (overwritten by cen/fn/vn only
  // after CG completes). 3*N3 = 9.44M floats <= 15.7M available past O1.
  float* r = out + O1;
  float* p = r + N3;
  float* q = p + N3;
  // partial sums + scalars after q (aligned: offset*4 bytes is mult of 8)
  double* partPQ = (double*)(out + O1 + 3*N3);   // 4096 doubles
  double* partRR = partPQ + 4096;                // 3072 doubles
  double* s      = partRR + 3072;                // s[0]=gamma s[1]=alpha s[2]=beta

  // init: x=0, r=p=u, gamma = <u,u>
  k_init<<<dim3(N4/256), dim3(256), 0, stream>>>((const float4*)u,
      (float4*)x, (float4*)r, (float4*)p, partRR);
  k_reduce<<<dim3(1), dim3(1024), 0, stream>>>(partRR, N4/256, s, 0);

  for (int it = 0; it < CG_ITERS; ++it) {
    k_mv<<<dim3(NV/256), dim3(256), 0, stream>>>(p, q, partPQ);
    k_reduce<<<dim3(1), dim3(1024), 0, stream>>>(partPQ, NV/256, s, 1);
    k_xr<<<dim3(N4/256), dim3(256), 0, stream>>>((float4*)x, (float4*)r,
        (const float4*)p, (const float4*)q, s, partRR);
    k_reduce<<<dim3(1), dim3(1024), 0, stream>>>(partRR, N4/256, s, 2);
    k_p<<<dim3(N4/256), dim3(256), 0, stream>>>((float4*)p, (const float4*)r, s);
  }

  k_faces<<<dim3((NF + 255)/256), dim3(256), 0, stream>>>(x, cen, fn);
  k_vn<<<dim3(NV/256), dim3(256), 0, stream>>>(fn, vn);
}